// Round 22
// baseline (166.113 us; speedup 1.0000x reference)
//
#include <hip/hip_runtime.h>
#include <cstdint>

typedef unsigned long long u64;
typedef unsigned short ushort_t;
typedef __attribute__((ext_vector_type(8))) short short8;
typedef __attribute__((ext_vector_type(4))) float f32x4;

#define B_TOTAL 16384
#define K_DIM   1025
#define O_DIM   1025
#define NWORDS  17        // ceil(1025/64)
#define NKT     34        // K tiles of 32 (covers 1088)
#define NFRAG   72        // n-fragments of 16 (covers 1152)
#define A_BYTES 8192      // per kt: 4 hi frags + 4 lo frags, 1 KB each
#define B_BYTES 73728     // per kt: 72 frags, 1 KB each (global, L2-resident)
#define NT      768       // 12 waves: 6 B-frags each (12*96 = 1152 exactly)
#define WFRAG   6
#define SMEM_BYTES 99328  // max(A dbuf 16 KB, epilogue layout ~99 KB)
#define FLAG_CAP 4096     // LDS flag list (mean ~225/block; 18x headroom)
#define L23_ROWS 16       // b-rows per l2l3 block (1024 blocks -> 4 blocks/CU)

// round-to-nearest-even f32 -> bf16 (finite inputs)
__device__ __forceinline__ ushort_t f2bf_rne(float f) {
  unsigned u = __float_as_uint(f);
  return (ushort_t)((u + 0x7fffu + ((u >> 16) & 1u)) >> 16);
}

// -------- pack all weight bit-rows (W0|W1|W2): bit=1 <=> w>=0, pad bits=1 --------
__global__ __launch_bounds__(256) void pack_all_kernel(const float* __restrict__ W0,
                                                       const float* __restrict__ W1,
                                                       const float* __restrict__ W2,
                                                       u64* __restrict__ w0b,
                                                       u64* __restrict__ w1b,
                                                       u64* __restrict__ w2b) {
  __shared__ unsigned char by[136];
  const int row = blockIdx.x, t = threadIdx.x;
  const float* src; u64* dst; int o;
  if (row < O_DIM)           { src = W0; dst = w0b; o = row; }
  else if (row < 2 * O_DIM)  { src = W1; dst = w1b; o = row - O_DIM; }
  else                       { src = W2; dst = w2b; o = 0; }
  if (t < 136) {
    const float* wr = src + (size_t)o * K_DIM;
    unsigned m = 0;
#pragma unroll
    for (int j = 0; j < 8; ++j) {
      int k = t * 8 + j;
      bool pos = (k < K_DIM) ? (wr[k] >= 0.0f) : true;
      m |= (unsigned)pos << j;
    }
    by[t] = (unsigned char)m;
  }
  __syncthreads();
  if (t < NWORDS) {
    u64 word = 0;
#pragma unroll
    for (int q = 0; q < 8; ++q) word |= (u64)by[t * 8 + q] << (8 * q);
    dst[(size_t)o * NWORDS + t] = word;
  }
}

// -------- prep_sbf: sign(W0) in MFMA-fragment order: [kt][nf][lane][8 shorts] --------
__global__ __launch_bounds__(256) void prep_sbf_kernel(const float* __restrict__ w0,
                                                       ushort_t* __restrict__ sbf) {
  const int t = threadIdx.x;
  const int f = blockIdx.x * 4 + (t >> 6);        // 0..2447 = kt*72+nf
  const int lane = t & 63;
  const int kt = f / NFRAG, nf = f % NFRAG;
  const int o = nf * 16 + (lane & 15);
  const int kbase = kt * 32 + (lane >> 4) * 8;
  short8 sv;
#pragma unroll
  for (int j = 0; j < 8; ++j) {
    int k = kbase + j;
    short v = 0;
    if (o < O_DIM && k < K_DIM)
      v = (short)((w0[(size_t)o * K_DIM + k] >= 0.0f) ? 0x3F80 : 0xBF80);
    sv[j] = v;
  }
  *(short8*)&sbf[(size_t)f * 512 + lane * 8] = sv;
}

// -------- fused layer1: 12 waves x 6 B-frags (3 waves/SIMD), r21 schedule --------
// Same 64x1152 block, same traffic, same conversion (t<512 only; waves 8-11
// skip convert and idle briefly at the barrier -- hidden at 3 waves/SIMD).
// lgkmcnt-only barriers (r21-proven); per-fragment rotating B reload.
// Conversion order and MFMA chain per acc element unchanged -> bit-identical.
__global__ __launch_bounds__(NT, 3) void l1_fused_kernel(
    const ushort_t* __restrict__ sbf, const float* __restrict__ x,
    const u64* __restrict__ w0b, u64* __restrict__ h1b) {
  extern __shared__ char smem[];
  const int p = blockIdx.x;
  const int t = threadIdx.x;
  const int wave = t >> 6, lane = t & 63;
  const int lr = lane & 15, lg = lane >> 4;
  const int b0 = p * 64;
  const int obase = wave * (WFRAG * 16);          // 96 cols per wave

  // conversion mapping (threads 0..511 only): slot u, hi (t<256) or lo (256<=t<512)
  const int u = t & 255;
  const int cmf = u >> 6, clane = u & 63;
  const int crow = cmf * 16 + (clane & 15);
  const int ckb0 = (clane >> 4) * 8;
  const bool isHi = (t < 256);
  const bool doConv = (t < 512);                  // wave-uniform
  const float* xrowC = x + (size_t)(b0 + crow) * K_DIM;
  const int convOff = ((t >= 256) ? 4096 : 0) + cmf * 1024 + clane * 16;

  const ushort_t* gB = sbf + (size_t)(wave * WFRAG) * 512 + lane * 8;

  f32x4 acc[4][WFRAG];
#pragma unroll
  for (int mf = 0; mf < 4; ++mf)
#pragma unroll
    for (int nfl = 0; nfl < WFRAG; ++nfl)
#pragma unroll
      for (int c = 0; c < 4; ++c) acc[mf][nfl][c] = 0.0f;

  float xv[8];
  float sAcc = 0.0f;
  short8 bX[WFRAG];

#define LOADX(KT)                                                              \
  if (doConv) {                                                                \
    int kb = (KT) * 32 + ckb0;                                                 \
    const float* xr = xrowC + kb;                                              \
    if (kb + 8 <= K_DIM) {                                                     \
      float4 a = *(const float4*)xr;                                           \
      float4 b = *(const float4*)(xr + 4);                                     \
      xv[0]=a.x; xv[1]=a.y; xv[2]=a.z; xv[3]=a.w;                              \
      xv[4]=b.x; xv[5]=b.y; xv[6]=b.z; xv[7]=b.w;                              \
    } else {                                                                   \
      _Pragma("unroll")                                                        \
      for (int j = 0; j < 8; ++j) xv[j] = (kb + j < K_DIM) ? xr[j] : 0.0f;     \
    }                                                                          \
  }

#define CONVERT_WRITE(DBUF)                                                    \
  if (doConv) {                                                                \
    short8 w8;                                                                 \
    if (isHi) {                                                                \
      _Pragma("unroll")                                                        \
      for (int j = 0; j < 8; ++j) {                                            \
        float v = xv[j];                                                       \
        sAcc += fabsf(v);                                                      \
        w8[j] = (short)f2bf_rne(v);                                            \
      }                                                                        \
    } else {                                                                   \
      _Pragma("unroll")                                                        \
      for (int j = 0; j < 8; ++j) {                                            \
        float v = xv[j];                                                       \
        ushort_t h = f2bf_rne(v);                                              \
        float hf = __uint_as_float((unsigned)h << 16);                         \
        w8[j] = (short)f2bf_rne(v - hf);                                       \
      }                                                                        \
    }                                                                          \
    *(short8*)((DBUF) + convOff) = w8;                                         \
  }

#define LOADB(KT)                                                              \
  {                                                                            \
    _Pragma("unroll")                                                          \
    for (int i = 0; i < WFRAG; ++i)                                            \
      bX[i] = *(const short8*)&gB[(size_t)(KT) * (B_BYTES / 2) + i * 512];     \
  }

// MFMA over bX for current kt; per-fragment reload of bX[nfl] for KTN (next kt)
#define MFMA_STEP(AOFF, KTN)                                                   \
  {                                                                            \
    const ushort_t* A = (const ushort_t*)(smem + (AOFF));                      \
    const ushort_t* gBn = gB + (size_t)(KTN) * (B_BYTES / 2);                  \
    short8 ah[4], al[4];                                                       \
    _Pragma("unroll")                                                          \
    for (int mf = 0; mf < 4; ++mf) {                                           \
      ah[mf] = *(const short8*)&A[mf * 512 + lane * 8];                        \
      al[mf] = *(const short8*)&A[(4 + mf) * 512 + lane * 8];                  \
    }                                                                          \
    _Pragma("unroll")                                                          \
    for (int nfl = 0; nfl < WFRAG; ++nfl) {                                    \
      short8 bv = bX[nfl];                                                     \
      bX[nfl] = *(const short8*)&gBn[nfl * 512];                               \
      _Pragma("unroll")                                                        \
      for (int mf = 0; mf < 4; ++mf) {                                         \
        acc[mf][nfl] = __builtin_amdgcn_mfma_f32_16x16x32_bf16(ah[mf], bv, acc[mf][nfl], 0, 0, 0); \
        acc[mf][nfl] = __builtin_amdgcn_mfma_f32_16x16x32_bf16(al[mf], bv, acc[mf][nfl], 0, 0, 0); \
      }                                                                        \
    }                                                                          \
  }

#define LDS_BARRIER()                                                          \
  {                                                                            \
    asm volatile("s_waitcnt lgkmcnt(0)" ::: "memory");                         \
    __builtin_amdgcn_s_barrier();                                              \
  }

  // prologue: kt=0 -> buf0; B(0) -> bX; pre-issue x(kt=1)
  LOADX(0); CONVERT_WRITE(smem);
  LOADB(0);
  LOADX(1);
  LDS_BARRIER();

  for (int kt = 0; kt < NKT; kt += 2) {
    // even step: convert kt+1 -> buf1 FIRST, refill xv with kt+2, compute kt from buf0
    {
      CONVERT_WRITE(smem + 8192);           // kt+1 (always valid: kt<=32 -> kt+1<=33)
      if (kt + 2 < NKT) LOADX(kt + 2);
      MFMA_STEP(0, kt + 1);
      LDS_BARRIER();
    }
    // odd step: convert kt+2 -> buf0, refill with kt+3, compute kt+1 from buf1
    {
      if (kt + 2 < NKT) CONVERT_WRITE(smem);
      if (kt + 3 < NKT) LOADX(kt + 3);
      const int ktn = (kt + 2 < NKT) ? (kt + 2) : (NKT - 1);
      MFMA_STEP(8192, ktn);
      LDS_BARRIER();
    }
  }
#undef LOADX
#undef CONVERT_WRITE
#undef LOADB
#undef MFMA_STEP
#undef LDS_BARRIER

  __syncthreads();   // full drain before LDS reuse by epilogue

  // ---- epilogue LDS layout (reuses the dynamic region) ----
  unsigned char* bits = (unsigned char*)smem;        // [64][1152]   0..73728
  u64*      hs    = (u64*)(smem + 73728);            // [64][17]     ..82432
  unsigned* list  = (unsigned*)(smem + 82432);       // FLAG_CAP u32 ..98816
  unsigned* lcnt  = (unsigned*)(smem + 98816);
  float*    errbL = (float*)(smem + 98832);          // 64 floats
  unsigned* hsw   = (unsigned*)hs;                   // u32 view for atomicXor

  // errb row-sums: hi threads own each row's values once; r12-identical tree
  sAcc += __shfl_xor(sAcc, 16, 64);
  sAcc += __shfl_xor(sAcc, 32, 64);
  if (t == 0) *lcnt = 0;
  if (isHi && lg == 0)
    errbL[crow] = sAcc * (1.02f / 65536.0f) + 0.125f;
  __syncthreads();

  float eb[4][4];
#pragma unroll
  for (int mf = 0; mf < 4; ++mf)
#pragma unroll
    for (int rg = 0; rg < 4; ++rg) eb[mf][rg] = errbL[mf * 16 + lg * 4 + rg];

#pragma unroll
  for (int mf = 0; mf < 4; ++mf)
#pragma unroll
    for (int nfl = 0; nfl < WFRAG; ++nfl)
#pragma unroll
      for (int rg = 0; rg < 4; ++rg) {
        int bl = mf * 16 + lg * 4 + rg;              // C/D: row = (lane>>4)*4 + reg
        int o  = obase + nfl * 16 + lr;              // C/D: col = lane & 15
        float lin = acc[mf][nfl][rg];
        unsigned abit = (lin >= 0.0f) ? 1u : 0u;
        bits[bl * 1152 + o] = (unsigned char)abit;
        if ((o < O_DIM) && (fabsf(lin) <= eb[mf][rg])) {
          unsigned idx = atomicAdd(lcnt, 1u);
          if (idx < FLAG_CAP)
            list[idx] = ((unsigned)bl << 12) | ((unsigned)o << 1) | abit;
        }
      }
  __syncthreads();

  // pack bits -> h1 words in LDS (pad bits = 1)
  for (int task = t; task < 64 * NWORDS; task += NT) {
    int row = task / NWORDS, w = task % NWORDS;
    u64 word = 0;
#pragma unroll
    for (int q = 0; q < 8; ++q) {
      u64 v = *(const u64*)&bits[row * 1152 + w * 64 + q * 8];
#pragma unroll
      for (int m = 0; m < 8; ++m)
        word |= ((v >> (8 * m)) & 1ull) << (q * 8 + m);
    }
    int rem = O_DIM - w * 64;
    if (rem < 64) word |= (~0ull << rem);
    hs[row * NWORDS + w] = word;
  }
  __syncthreads();

  // in-block exact recompute of flagged elements (bitwise = reference)
  {
    unsigned n = *lcnt; if (n > FLAG_CAP) n = FLAG_CAP;
    for (unsigned i = t; i < n; i += NT) {
      unsigned en = list[i];
      int bl = (int)(en >> 12), o = (int)((en >> 1) & 0x7ffu);
      unsigned abit = en & 1u;
      const float* xr = x + (size_t)(b0 + bl) * K_DIM;
      const u64* wr = w0b + (size_t)o * NWORDS;
      float a = 0.0f;
      for (int j = 0; j < 16; ++j) {    // k strictly ascending, single accumulator
        u64 wd = wr[j];
#pragma unroll
        for (int m = 0; m < 64; ++m) {
          float v = xr[j * 64 + m];
          unsigned neg = ((unsigned)(wd >> m) & 1u) ^ 1u;
          a += __uint_as_float(__float_as_uint(v) ^ (neg << 31));
        }
      }
      {
        u64 wd = wr[16];
        float v = xr[1024];
        unsigned neg = ((unsigned)wd & 1u) ^ 1u;
        a += __uint_as_float(__float_as_uint(v) ^ (neg << 31));
      }
      unsigned nb = (a >= 0.0f) ? 1u : 0u;
      if (nb != abit)
        atomicXor(&hsw[bl * 34 + (o >> 5)], 1u << (o & 31));
    }
  }
  __syncthreads();

  // corrected h1 -> global (coalesced)
  for (int task = t; task < 64 * NWORDS; task += NT)
    h1b[(size_t)b0 * NWORDS + task] = hs[task];
}

// -------- layers 2+3: XOR+popcount (exact); r7-proven lean-VGPR version --------
__global__ __launch_bounds__(256) void l2l3_kernel(const u64* __restrict__ h1b,
                                                   const u64* __restrict__ w1b,
                                                   const u64* __restrict__ w2b,
                                                   float* __restrict__ out) {
  __shared__ u64 hs[L23_ROWS][NWORDS];
  __shared__ u64 h2[L23_ROWS][NWORDS];
  const int bt = blockIdx.x;                 // 1024 blocks x 16 rows
  const int t = threadIdx.x;
  for (int i = t; i < L23_ROWS * NWORDS; i += 256)
    hs[i / NWORDS][i % NWORDS] = h1b[(size_t)(bt * L23_ROWS + i / NWORDS) * NWORDS + i % NWORDS];
  __syncthreads();

  const int w = t >> 6, l = t & 63;
  for (int oc = w; oc < NWORDS; oc += 4) {
    int o = oc * 64 + l;
    bool valid = (o < O_DIM);
    int orow = valid ? o : (O_DIM - 1);
    u64 wb[NWORDS];
#pragma unroll
    for (int j = 0; j < NWORDS; ++j) wb[j] = w1b[(size_t)orow * NWORDS + j];
    for (int b = 0; b < L23_ROWS; b += 2) {   // no unroll: keep regs lean; 2 chains for ILP
      int p0 = 0, p1 = 0;
#pragma unroll
      for (int j = 0; j < NWORDS; ++j) {
        p0 += __popcll(hs[b + 0][j] ^ wb[j]);
        p1 += __popcll(hs[b + 1][j] ^ wb[j]);
      }
      u64 m0 = __ballot(valid ? (K_DIM - 2 * p0 >= 0) : true);   // pad bits = 1
      u64 m1 = __ballot(valid ? (K_DIM - 2 * p1 >= 0) : true);
      if (l == 0) h2[b + 0][oc] = m0;
      if (l == 1) h2[b + 1][oc] = m1;
    }
  }
  __syncthreads();
  if (t < L23_ROWS) {
    int p = 0;
#pragma unroll
    for (int j = 0; j < NWORDS; ++j) p += __popcll(h2[t][j] ^ w2b[j]);
    out[bt * L23_ROWS + t] = ((K_DIM - 2 * p) >= 0) ? 1.0f : 0.0f;
  }
}

extern "C" void kernel_launch(void* const* d_in, const int* in_sizes, int n_in,
                              void* d_out, int out_size, void* d_ws, size_t ws_size,
                              hipStream_t stream) {
  const float* x  = (const float*)d_in[0];
  const float* W0 = (const float*)d_in[1];
  const float* W1 = (const float*)d_in[2];
  const float* W2 = (const float*)d_in[3];
  float* out = (float*)d_out;

  char* ws = (char*)d_ws;
  u64*      w0b  = (u64*)(ws);                   //       0 .. 139776
  u64*      w1b  = (u64*)(ws + 139776);          // .. 279552
  u64*      w2b  = (u64*)(ws + 279552);          // .. 279808
  u64*      h1b  = (u64*)(ws + 280064);          // .. 2508288
  ushort_t* sbf  = (ushort_t*)(ws + 2508288);    // .. 5015040

  static bool attr_set = false;
  if (!attr_set) {
    hipFuncSetAttribute((const void*)l1_fused_kernel,
                        hipFuncAttributeMaxDynamicSharedMemorySize, SMEM_BYTES);
    attr_set = true;
  }

  pack_all_kernel<<<2 * O_DIM + 1, 256, 0, stream>>>(W0, W1, W2, w0b, w1b, w2b);
  prep_sbf_kernel<<<NKT * NFRAG / 4, 256, 0, stream>>>(W0, sbf);
  l1_fused_kernel<<<B_TOTAL / 64, NT, SMEM_BYTES, stream>>>(sbf, x, w0b, h1b);
  l2l3_kernel<<<B_TOTAL / L23_ROWS, 256, 0, stream>>>(h1b, w1b, w2b, out);
}

// Round 23
// 162.650 us; speedup vs baseline: 1.0213x; 1.0213x over previous
//
#include <hip/hip_runtime.h>
#include <cstdint>

typedef unsigned long long u64;
typedef unsigned short ushort_t;
typedef __attribute__((ext_vector_type(8))) short short8;
typedef __attribute__((ext_vector_type(4))) float f32x4;

#define B_TOTAL 16384
#define K_DIM   1025
#define O_DIM   1025
#define NWORDS  17        // ceil(1025/64)
#define NKT     34        // K tiles of 32 (covers 1088); even -> clean kt pairs
#define NFRAG   72        // n-fragments of 16 (covers 1152)
#define A_BYTES 8192      // per kt: 4 hi frags + 4 lo frags, 1 KB each
#define B_BYTES 73728     // per kt: 72 frags, 1 KB each (global, L2-resident)
#define SMEM_BYTES 99328  // max(A quad-buf 32 KB, epilogue layout ~99 KB)
#define FLAG_CAP 4096     // LDS flag list (mean ~225/block; 18x headroom)
#define L23_ROWS 16       // b-rows per l2l3 block (1024 blocks -> 4 blocks/CU)

// round-to-nearest-even f32 -> bf16 (finite inputs)
__device__ __forceinline__ ushort_t f2bf_rne(float f) {
  unsigned u = __float_as_uint(f);
  return (ushort_t)((u + 0x7fffu + ((u >> 16) & 1u)) >> 16);
}

// -------- pack all weight bit-rows (W0|W1|W2): bit=1 <=> w>=0, pad bits=1 --------
__global__ __launch_bounds__(256) void pack_all_kernel(const float* __restrict__ W0,
                                                       const float* __restrict__ W1,
                                                       const float* __restrict__ W2,
                                                       u64* __restrict__ w0b,
                                                       u64* __restrict__ w1b,
                                                       u64* __restrict__ w2b) {
  __shared__ unsigned char by[136];
  const int row = blockIdx.x, t = threadIdx.x;
  const float* src; u64* dst; int o;
  if (row < O_DIM)           { src = W0; dst = w0b; o = row; }
  else if (row < 2 * O_DIM)  { src = W1; dst = w1b; o = row - O_DIM; }
  else                       { src = W2; dst = w2b; o = 0; }
  if (t < 136) {
    const float* wr = src + (size_t)o * K_DIM;
    unsigned m = 0;
#pragma unroll
    for (int j = 0; j < 8; ++j) {
      int k = t * 8 + j;
      bool pos = (k < K_DIM) ? (wr[k] >= 0.0f) : true;
      m |= (unsigned)pos << j;
    }
    by[t] = (unsigned char)m;
  }
  __syncthreads();
  if (t < NWORDS) {
    u64 word = 0;
#pragma unroll
    for (int q = 0; q < 8; ++q) word |= (u64)by[t * 8 + q] << (8 * q);
    dst[(size_t)o * NWORDS + t] = word;
  }
}

// -------- prep_sbf: sign(W0) in MFMA-fragment order: [kt][nf][lane][8 shorts] --------
__global__ __launch_bounds__(256) void prep_sbf_kernel(const float* __restrict__ w0,
                                                       ushort_t* __restrict__ sbf) {
  const int t = threadIdx.x;
  const int f = blockIdx.x * 4 + (t >> 6);        // 0..2447 = kt*72+nf
  const int lane = t & 63;
  const int kt = f / NFRAG, nf = f % NFRAG;
  const int o = nf * 16 + (lane & 15);
  const int kbase = kt * 32 + (lane >> 4) * 8;
  short8 sv;
#pragma unroll
  for (int j = 0; j < 8; ++j) {
    int k = kbase + j;
    short v = 0;
    if (o < O_DIM && k < K_DIM)
      v = (short)((w0[(size_t)o * K_DIM + k] >= 0.0f) ? 0x3F80 : 0xBF80);
    sv[j] = v;
  }
  *(short8*)&sbf[(size_t)f * 512 + lane * 8] = sv;
}

// -------- fused layer1 (r21 base): 4 A-buffers, 2 kt per phase, barrier every 2 kt --------
// Barrier overhead (~4.3k cyc/phase measured r21) amortized over 2 kt of MFMA.
// lgkmcnt-only barriers; rotating per-fragment B reload spans the 2-step phase.
// Conversion order per thread strictly kt-ascending; MFMA chain per acc element
// unchanged -> bit-identical results.
__global__ __launch_bounds__(512, 1) void l1_fused_kernel(
    const ushort_t* __restrict__ sbf, const float* __restrict__ x,
    const u64* __restrict__ w0b, u64* __restrict__ h1b) {
  extern __shared__ char smem[];
  const int p = blockIdx.x;
  const int t = threadIdx.x;
  const int wave = t >> 6, lane = t & 63;
  const int lr = lane & 15, lg = lane >> 4;
  const int b0 = p * 64;
  const int obase = wave * 144;

  // conversion mapping: slot u, hi (t<256) or lo (t>=256); one linear b128 write each
  const int u = t & 255;
  const int cmf = u >> 6, clane = u & 63;
  const int crow = cmf * 16 + (clane & 15);
  const int ckb0 = (clane >> 4) * 8;
  const bool isLo = (t >= 256);                   // wave-uniform
  const float* xrowC = x + (size_t)(b0 + crow) * K_DIM;
  const int convOff = (isLo ? 4096 : 0) + cmf * 1024 + clane * 16;

  const ushort_t* gB = sbf + (size_t)(wave * 9) * 512 + lane * 8;

  f32x4 acc[4][9];
#pragma unroll
  for (int mf = 0; mf < 4; ++mf)
#pragma unroll
    for (int nfl = 0; nfl < 9; ++nfl)
#pragma unroll
      for (int c = 0; c < 4; ++c) acc[mf][nfl][c] = 0.0f;

  float xvA[8], xvB[8];
  float sAcc = 0.0f;
  short8 bX[9];

#define LOADX(KT, XV)                                                          \
  {                                                                            \
    int kb = (KT) * 32 + ckb0;                                                 \
    const float* xr = xrowC + kb;                                              \
    if (kb + 8 <= K_DIM) {                                                     \
      float4 a = *(const float4*)xr;                                           \
      float4 b = *(const float4*)(xr + 4);                                     \
      (XV)[0]=a.x; (XV)[1]=a.y; (XV)[2]=a.z; (XV)[3]=a.w;                      \
      (XV)[4]=b.x; (XV)[5]=b.y; (XV)[6]=b.z; (XV)[7]=b.w;                      \
    } else {                                                                   \
      _Pragma("unroll")                                                        \
      for (int j = 0; j < 8; ++j) (XV)[j] = (kb + j < K_DIM) ? xr[j] : 0.0f;   \
    }                                                                          \
  }

#define CONVERT_WRITE(DBUF, XV)                                                \
  {                                                                            \
    short8 w8;                                                                 \
    if (!isLo) {                                                               \
      _Pragma("unroll")                                                        \
      for (int j = 0; j < 8; ++j) {                                            \
        float v = (XV)[j];                                                     \
        sAcc += fabsf(v);                                                      \
        w8[j] = (short)f2bf_rne(v);                                            \
      }                                                                        \
    } else {                                                                   \
      _Pragma("unroll")                                                        \
      for (int j = 0; j < 8; ++j) {                                            \
        float v = (XV)[j];                                                     \
        ushort_t h = f2bf_rne(v);                                              \
        float hf = __uint_as_float((unsigned)h << 16);                         \
        w8[j] = (short)f2bf_rne(v - hf);                                       \
      }                                                                        \
    }                                                                          \
    *(short8*)((DBUF) + convOff) = w8;                                         \
  }

#define LOADB(KT)                                                              \
  {                                                                            \
    _Pragma("unroll")                                                          \
    for (int i = 0; i < 9; ++i)                                                \
      bX[i] = *(const short8*)&gB[(size_t)(KT) * (B_BYTES / 2) + i * 512];     \
  }

// MFMA over bX for current kt; per-fragment reload of bX[nfl] for KTN (next kt)
#define MFMA_STEP(AOFF, KTN)                                                   \
  {                                                                            \
    const ushort_t* A = (const ushort_t*)(smem + (AOFF));                      \
    const ushort_t* gBn = gB + (size_t)(KTN) * (B_BYTES / 2);                  \
    short8 ah[4], al[4];                                                       \
    _Pragma("unroll")                                                          \
    for (int mf = 0; mf < 4; ++mf) {                                           \
      ah[mf] = *(const short8*)&A[mf * 512 + lane * 8];                        \
      al[mf] = *(const short8*)&A[(4 + mf) * 512 + lane * 8];                  \
    }                                                                          \
    _Pragma("unroll")                                                          \
    for (int nfl = 0; nfl < 9; ++nfl) {                                        \
      short8 bv = bX[nfl];                                                     \
      bX[nfl] = *(const short8*)&gBn[nfl * 512];                               \
      _Pragma("unroll")                                                        \
      for (int mf = 0; mf < 4; ++mf) {                                         \
        acc[mf][nfl] = __builtin_amdgcn_mfma_f32_16x16x32_bf16(ah[mf], bv, acc[mf][nfl], 0, 0, 0); \
        acc[mf][nfl] = __builtin_amdgcn_mfma_f32_16x16x32_bf16(al[mf], bv, acc[mf][nfl], 0, 0, 0); \
      }                                                                        \
    }                                                                          \
  }

#define LDS_BARRIER()                                                          \
  {                                                                            \
    asm volatile("s_waitcnt lgkmcnt(0)" ::: "memory");                         \
    __builtin_amdgcn_s_barrier();                                              \
  }

  // prologue: kt0 -> buf(0), kt1 -> buf(8192); B(0) -> bX; pre-issue x(2),x(3)
  LOADX(0, xvA); LOADX(1, xvB);
  CONVERT_WRITE(smem, xvA);
  CONVERT_WRITE(smem + 8192, xvB);
  LOADB(0);
  LOADX(2, xvA); LOADX(3, xvB);
  LDS_BARRIER();

  int cur = 0;  // read-pair index: pair base = cur*16384
  for (int kt = 0; kt < NKT; kt += 2) {
    const int rd = cur * 16384;
    const int wr = (cur ^ 1) * 16384;
    // convert next pair (kt+2, kt+3) into the write pair; refill xv with kt+4/kt+5
    if (kt + 2 < NKT) CONVERT_WRITE(smem + wr, xvA);
    if (kt + 3 < NKT) CONVERT_WRITE(smem + wr + 8192, xvB);
    if (kt + 4 < NKT) LOADX(kt + 4, xvA);
    if (kt + 5 < NKT) LOADX(kt + 5, xvB);
    // compute kt (B rotates to kt+1), then kt+1 (B rotates to kt+2)
    MFMA_STEP(rd, kt + 1);
    {
      const int ktn = (kt + 2 < NKT) ? (kt + 2) : (NKT - 1);
      MFMA_STEP(rd + 8192, ktn);
    }
    LDS_BARRIER();
    cur ^= 1;
  }
#undef LOADX
#undef CONVERT_WRITE
#undef LOADB
#undef MFMA_STEP
#undef LDS_BARRIER

  __syncthreads();   // full drain before LDS reuse by epilogue

  // ---- epilogue LDS layout (reuses the dynamic region) ----
  unsigned char* bits = (unsigned char*)smem;        // [64][1152]   0..73728
  u64*      hs    = (u64*)(smem + 73728);            // [64][17]     ..82432
  unsigned* list  = (unsigned*)(smem + 82432);       // FLAG_CAP u32 ..98816
  unsigned* lcnt  = (unsigned*)(smem + 98816);
  float*    errbL = (float*)(smem + 98832);          // 64 floats
  unsigned* hsw   = (unsigned*)hs;                   // u32 view for atomicXor

  // errb row-sums: hi threads own each row's values once; r12-identical tree
  sAcc += __shfl_xor(sAcc, 16, 64);
  sAcc += __shfl_xor(sAcc, 32, 64);
  if (t == 0) *lcnt = 0;
  if (!isLo && lg == 0)
    errbL[crow] = sAcc * (1.02f / 65536.0f) + 0.125f;
  __syncthreads();

  float eb[4][4];
#pragma unroll
  for (int mf = 0; mf < 4; ++mf)
#pragma unroll
    for (int rg = 0; rg < 4; ++rg) eb[mf][rg] = errbL[mf * 16 + lg * 4 + rg];

#pragma unroll
  for (int mf = 0; mf < 4; ++mf)
#pragma unroll
    for (int nfl = 0; nfl < 9; ++nfl)
#pragma unroll
      for (int rg = 0; rg < 4; ++rg) {
        int bl = mf * 16 + lg * 4 + rg;              // C/D: row = (lane>>4)*4 + reg
        int o  = obase + nfl * 16 + lr;              // C/D: col = lane & 15
        float lin = acc[mf][nfl][rg];
        unsigned abit = (lin >= 0.0f) ? 1u : 0u;
        bits[bl * 1152 + o] = (unsigned char)abit;
        if ((o < O_DIM) && (fabsf(lin) <= eb[mf][rg])) {
          unsigned idx = atomicAdd(lcnt, 1u);
          if (idx < FLAG_CAP)
            list[idx] = ((unsigned)bl << 12) | ((unsigned)o << 1) | abit;
        }
      }
  __syncthreads();

  // pack bits -> h1 words in LDS (pad bits = 1)
  for (int task = t; task < 64 * NWORDS; task += 512) {
    int row = task / NWORDS, w = task % NWORDS;
    u64 word = 0;
#pragma unroll
    for (int q = 0; q < 8; ++q) {
      u64 v = *(const u64*)&bits[row * 1152 + w * 64 + q * 8];
#pragma unroll
      for (int m = 0; m < 8; ++m)
        word |= ((v >> (8 * m)) & 1ull) << (q * 8 + m);
    }
    int rem = O_DIM - w * 64;
    if (rem < 64) word |= (~0ull << rem);
    hs[row * NWORDS + w] = word;
  }
  __syncthreads();

  // in-block exact recompute of flagged elements (bitwise = reference)
  {
    unsigned n = *lcnt; if (n > FLAG_CAP) n = FLAG_CAP;
    for (unsigned i = t; i < n; i += 512) {
      unsigned en = list[i];
      int bl = (int)(en >> 12), o = (int)((en >> 1) & 0x7ffu);
      unsigned abit = en & 1u;
      const float* xr = x + (size_t)(b0 + bl) * K_DIM;
      const u64* wr = w0b + (size_t)o * NWORDS;
      float a = 0.0f;
      for (int j = 0; j < 16; ++j) {    // k strictly ascending, single accumulator
        u64 wd = wr[j];
#pragma unroll
        for (int m = 0; m < 64; ++m) {
          float v = xr[j * 64 + m];
          unsigned neg = ((unsigned)(wd >> m) & 1u) ^ 1u;
          a += __uint_as_float(__float_as_uint(v) ^ (neg << 31));
        }
      }
      {
        u64 wd = wr[16];
        float v = xr[1024];
        unsigned neg = ((unsigned)wd & 1u) ^ 1u;
        a += __uint_as_float(__float_as_uint(v) ^ (neg << 31));
      }
      unsigned nb = (a >= 0.0f) ? 1u : 0u;
      if (nb != abit)
        atomicXor(&hsw[bl * 34 + (o >> 5)], 1u << (o & 31));
    }
  }
  __syncthreads();

  // corrected h1 -> global (coalesced)
  for (int task = t; task < 64 * NWORDS; task += 512)
    h1b[(size_t)b0 * NWORDS + task] = hs[task];
}

// -------- layers 2+3: XOR+popcount (exact); r7-proven lean-VGPR version --------
__global__ __launch_bounds__(256) void l2l3_kernel(const u64* __restrict__ h1b,
                                                   const u64* __restrict__ w1b,
                                                   const u64* __restrict__ w2b,
                                                   float* __restrict__ out) {
  __shared__ u64 hs[L23_ROWS][NWORDS];
  __shared__ u64 h2[L23_ROWS][NWORDS];
  const int bt = blockIdx.x;                 // 1024 blocks x 16 rows
  const int t = threadIdx.x;
  for (int i = t; i < L23_ROWS * NWORDS; i += 256)
    hs[i / NWORDS][i % NWORDS] = h1b[(size_t)(bt * L23_ROWS + i / NWORDS) * NWORDS + i % NWORDS];
  __syncthreads();

  const int w = t >> 6, l = t & 63;
  for (int oc = w; oc < NWORDS; oc += 4) {
    int o = oc * 64 + l;
    bool valid = (o < O_DIM);
    int orow = valid ? o : (O_DIM - 1);
    u64 wb[NWORDS];
#pragma unroll
    for (int j = 0; j < NWORDS; ++j) wb[j] = w1b[(size_t)orow * NWORDS + j];
    for (int b = 0; b < L23_ROWS; b += 2) {   // no unroll: keep regs lean; 2 chains for ILP
      int p0 = 0, p1 = 0;
#pragma unroll
      for (int j = 0; j < NWORDS; ++j) {
        p0 += __popcll(hs[b + 0][j] ^ wb[j]);
        p1 += __popcll(hs[b + 1][j] ^ wb[j]);
      }
      u64 m0 = __ballot(valid ? (K_DIM - 2 * p0 >= 0) : true);   // pad bits = 1
      u64 m1 = __ballot(valid ? (K_DIM - 2 * p1 >= 0) : true);
      if (l == 0) h2[b + 0][oc] = m0;
      if (l == 1) h2[b + 1][oc] = m1;
    }
  }
  __syncthreads();
  if (t < L23_ROWS) {
    int p = 0;
#pragma unroll
    for (int j = 0; j < NWORDS; ++j) p += __popcll(h2[t][j] ^ w2b[j]);
    out[bt * L23_ROWS + t] = ((K_DIM - 2 * p) >= 0) ? 1.0f : 0.0f;
  }
}

extern "C" void kernel_launch(void* const* d_in, const int* in_sizes, int n_in,
                              void* d_out, int out_size, void* d_ws, size_t ws_size,
                              hipStream_t stream) {
  const float* x  = (const float*)d_in[0];
  const float* W0 = (const float*)d_in[1];
  const float* W1 = (const float*)d_in[2];
  const float* W2 = (const float*)d_in[3];
  float* out = (float*)d_out;

  char* ws = (char*)d_ws;
  u64*      w0b  = (u64*)(ws);                   //       0 .. 139776
  u64*      w1b  = (u64*)(ws + 139776);          // .. 279552
  u64*      w2b  = (u64*)(ws + 279552);          // .. 279808
  u64*      h1b  = (u64*)(ws + 280064);          // .. 2508288
  ushort_t* sbf  = (ushort_t*)(ws + 2508288);    // .. 5015040

  static bool attr_set = false;
  if (!attr_set) {
    hipFuncSetAttribute((const void*)l1_fused_kernel,
                        hipFuncAttributeMaxDynamicSharedMemorySize, SMEM_BYTES);
    attr_set = true;
  }

  pack_all_kernel<<<2 * O_DIM + 1, 256, 0, stream>>>(W0, W1, W2, w0b, w1b, w2b);
  prep_sbf_kernel<<<NKT * NFRAG / 4, 256, 0, stream>>>(W0, sbf);
  l1_fused_kernel<<<B_TOTAL / 64, 512, SMEM_BYTES, stream>>>(sbf, x, w0b, h1b);
  l2l3_kernel<<<B_TOTAL / L23_ROWS, 256, 0, stream>>>(h1b, w1b, w2b, out);
}

// Round 24
// 150.284 us; speedup vs baseline: 1.1053x; 1.0823x over previous
//
#include <hip/hip_runtime.h>
#include <cstdint>

typedef unsigned long long u64;
typedef unsigned short ushort_t;
typedef __attribute__((ext_vector_type(8))) short short8;
typedef __attribute__((ext_vector_type(4))) float f32x4;

#define B_TOTAL 16384
#define K_DIM   1025
#define O_DIM   1025
#define NWORDS  17        // ceil(1025/64)
#define NKT     34        // K tiles of 32 (covers 1088)
#define NFRAG   72        // n-fragments of 16 (covers 1152)
#define A_BYTES 8192      // per kt: 4 hi frags + 4 lo frags, 1 KB each
#define B_BYTES 73728     // per kt: 72 frags, 1 KB each (global, L2-resident)
#define SMEM_BYTES 99328  // max(A dbuf 16 KB, epilogue layout ~99 KB)
#define FLAG_CAP 4096     // LDS flag list (mean ~225/block; 18x headroom)
#define L23_ROWS 16       // b-rows per l2l3 block (1024 blocks -> 4 blocks/CU)
#define PACK_BLOCKS (2 * O_DIM + 1)          // 2051 weight-pack rows
#define SBF_BLOCKS  (NKT * NFRAG / 4)        // 612 sbf fragment-quads

// round-to-nearest-even f32 -> bf16 (finite inputs)
__device__ __forceinline__ ushort_t f2bf_rne(float f) {
  unsigned u = __float_as_uint(f);
  return (ushort_t)((u + 0x7fffu + ((u >> 16) & 1u)) >> 16);
}

// -------- merged weight prep: [0,2051) pack bit-rows | [2051,2663) sbf frags --------
// (both compute-light 256-thread bodies with disjoint outputs; safe merge)
__global__ __launch_bounds__(256) void prep_w_kernel(const float* __restrict__ W0,
                                                     const float* __restrict__ W1,
                                                     const float* __restrict__ W2,
                                                     u64* __restrict__ w0b,
                                                     u64* __restrict__ w1b,
                                                     u64* __restrict__ w2b,
                                                     ushort_t* __restrict__ sbf) {
  __shared__ unsigned char by[136];
  const int bid = blockIdx.x, t = threadIdx.x;

  if (bid < PACK_BLOCKS) {
    // pack bit-rows: bit=1 <=> w>=0, pad bits=1
    const int row = bid;
    const float* src; u64* dst; int o;
    if (row < O_DIM)           { src = W0; dst = w0b; o = row; }
    else if (row < 2 * O_DIM)  { src = W1; dst = w1b; o = row - O_DIM; }
    else                       { src = W2; dst = w2b; o = 0; }
    if (t < 136) {
      const float* wr = src + (size_t)o * K_DIM;
      unsigned m = 0;
#pragma unroll
      for (int j = 0; j < 8; ++j) {
        int k = t * 8 + j;
        bool pos = (k < K_DIM) ? (wr[k] >= 0.0f) : true;
        m |= (unsigned)pos << j;
      }
      by[t] = (unsigned char)m;
    }
    __syncthreads();
    if (t < NWORDS) {
      u64 word = 0;
#pragma unroll
      for (int q = 0; q < 8; ++q) word |= (u64)by[t * 8 + q] << (8 * q);
      dst[(size_t)o * NWORDS + t] = word;
    }
    return;
  }

  // sbf: sign(W0) in MFMA-fragment order [kt][nf][lane][8 shorts]
  const int f = (bid - PACK_BLOCKS) * 4 + (t >> 6);   // 0..2447 = kt*72+nf
  const int lane = t & 63;
  const int kt = f / NFRAG, nf = f % NFRAG;
  const int o = nf * 16 + (lane & 15);
  const int kbase = kt * 32 + (lane >> 4) * 8;
  short8 sv;
#pragma unroll
  for (int j = 0; j < 8; ++j) {
    int k = kbase + j;
    short v = 0;
    if (o < O_DIM && k < K_DIM)
      v = (short)((W0[(size_t)o * K_DIM + k] >= 0.0f) ? 0x3F80 : 0xBF80);
    sv[j] = v;
  }
  *(short8*)&sbf[(size_t)f * 512 + lane * 8] = sv;
}

// -------- fused layer1 (r21-proven): lgkmcnt-only barriers; convert at step start --------
// T4-minimal: inter-step barrier orders ONLY LDS (A-buffer handoff) via
// s_waitcnt lgkmcnt(0) + raw s_barrier -- x-loads and rotating B reloads stay
// in flight across it. Convert at step START (overlaps post-barrier LDS-read
// burst). Conversion order 0..33 and MFMA chain unchanged -> bit-identical.
__global__ __launch_bounds__(512, 1) void l1_fused_kernel(
    const ushort_t* __restrict__ sbf, const float* __restrict__ x,
    const u64* __restrict__ w0b, u64* __restrict__ h1b) {
  extern __shared__ char smem[];
  const int p = blockIdx.x;
  const int t = threadIdx.x;
  const int wave = t >> 6, lane = t & 63;
  const int lr = lane & 15, lg = lane >> 4;
  const int b0 = p * 64;
  const int obase = wave * 144;

  // conversion mapping: slot u, hi (t<256) or lo (t>=256); one linear b128 write each
  const int u = t & 255;
  const int cmf = u >> 6, clane = u & 63;
  const int crow = cmf * 16 + (clane & 15);
  const int ckb0 = (clane >> 4) * 8;
  const bool isLo = (t >= 256);                   // wave-uniform
  const float* xrowC = x + (size_t)(b0 + crow) * K_DIM;
  const int convOff = (isLo ? 4096 : 0) + cmf * 1024 + clane * 16;

  const ushort_t* gB = sbf + (size_t)(wave * 9) * 512 + lane * 8;

  f32x4 acc[4][9];
#pragma unroll
  for (int mf = 0; mf < 4; ++mf)
#pragma unroll
    for (int nfl = 0; nfl < 9; ++nfl)
#pragma unroll
      for (int c = 0; c < 4; ++c) acc[mf][nfl][c] = 0.0f;

  float xv[8];
  float sAcc = 0.0f;
  short8 bX[9];

#define LOADX(KT)                                                              \
  {                                                                            \
    int kb = (KT) * 32 + ckb0;                                                 \
    const float* xr = xrowC + kb;                                              \
    if (kb + 8 <= K_DIM) {                                                     \
      float4 a = *(const float4*)xr;                                           \
      float4 b = *(const float4*)(xr + 4);                                     \
      xv[0]=a.x; xv[1]=a.y; xv[2]=a.z; xv[3]=a.w;                              \
      xv[4]=b.x; xv[5]=b.y; xv[6]=b.z; xv[7]=b.w;                              \
    } else {                                                                   \
      _Pragma("unroll")                                                        \
      for (int j = 0; j < 8; ++j) xv[j] = (kb + j < K_DIM) ? xr[j] : 0.0f;     \
    }                                                                          \
  }

#define CONVERT_WRITE(DBUF)                                                    \
  {                                                                            \
    short8 w8;                                                                 \
    if (!isLo) {                                                               \
      _Pragma("unroll")                                                        \
      for (int j = 0; j < 8; ++j) {                                            \
        float v = xv[j];                                                       \
        sAcc += fabsf(v);                                                      \
        w8[j] = (short)f2bf_rne(v);                                            \
      }                                                                        \
    } else {                                                                   \
      _Pragma("unroll")                                                        \
      for (int j = 0; j < 8; ++j) {                                            \
        float v = xv[j];                                                       \
        ushort_t h = f2bf_rne(v);                                              \
        float hf = __uint_as_float((unsigned)h << 16);                         \
        w8[j] = (short)f2bf_rne(v - hf);                                       \
      }                                                                        \
    }                                                                          \
    *(short8*)((DBUF) + convOff) = w8;                                         \
  }

#define LOADB(KT)                                                              \
  {                                                                            \
    _Pragma("unroll")                                                          \
    for (int i = 0; i < 9; ++i)                                                \
      bX[i] = *(const short8*)&gB[(size_t)(KT) * (B_BYTES / 2) + i * 512];     \
  }

// MFMA over bX for current kt; per-fragment reload of bX[nfl] for KTN (next kt)
#define MFMA_STEP(AOFF, KTN)                                                   \
  {                                                                            \
    const ushort_t* A = (const ushort_t*)(smem + (AOFF));                      \
    const ushort_t* gBn = gB + (size_t)(KTN) * (B_BYTES / 2);                  \
    short8 ah[4], al[4];                                                       \
    _Pragma("unroll")                                                          \
    for (int mf = 0; mf < 4; ++mf) {                                           \
      ah[mf] = *(const short8*)&A[mf * 512 + lane * 8];                        \
      al[mf] = *(const short8*)&A[(4 + mf) * 512 + lane * 8];                  \
    }                                                                          \
    _Pragma("unroll")                                                          \
    for (int nfl = 0; nfl < 9; ++nfl) {                                        \
      short8 bv = bX[nfl];                                                     \
      bX[nfl] = *(const short8*)&gBn[nfl * 512];                               \
      _Pragma("unroll")                                                        \
      for (int mf = 0; mf < 4; ++mf) {                                         \
        acc[mf][nfl] = __builtin_amdgcn_mfma_f32_16x16x32_bf16(ah[mf], bv, acc[mf][nfl], 0, 0, 0); \
        acc[mf][nfl] = __builtin_amdgcn_mfma_f32_16x16x32_bf16(al[mf], bv, acc[mf][nfl], 0, 0, 0); \
      }                                                                        \
    }                                                                          \
  }

#define LDS_BARRIER()                                                          \
  {                                                                            \
    asm volatile("s_waitcnt lgkmcnt(0)" ::: "memory");                         \
    __builtin_amdgcn_s_barrier();                                              \
  }

  // prologue: kt=0 -> buf0; B(0) -> bX; pre-issue x(kt=1)
  LOADX(0); CONVERT_WRITE(smem);
  LOADB(0);
  LOADX(1);
  LDS_BARRIER();

  for (int kt = 0; kt < NKT; kt += 2) {
    // even step: convert kt+1 -> buf1 FIRST, refill xv with kt+2, compute kt from buf0
    {
      CONVERT_WRITE(smem + 8192);           // kt+1 (always valid: kt<=32 -> kt+1<=33)
      if (kt + 2 < NKT) LOADX(kt + 2);
      MFMA_STEP(0, kt + 1);
      LDS_BARRIER();
    }
    // odd step: convert kt+2 -> buf0, refill with kt+3, compute kt+1 from buf1
    {
      if (kt + 2 < NKT) CONVERT_WRITE(smem);
      if (kt + 3 < NKT) LOADX(kt + 3);
      const int ktn = (kt + 2 < NKT) ? (kt + 2) : (NKT - 1);
      MFMA_STEP(8192, ktn);
      LDS_BARRIER();
    }
  }
#undef LOADX
#undef CONVERT_WRITE
#undef LOADB
#undef MFMA_STEP
#undef LDS_BARRIER

  __syncthreads();   // full drain before LDS reuse by epilogue

  // ---- epilogue LDS layout (reuses the dynamic region) ----
  unsigned char* bits = (unsigned char*)smem;        // [64][1152]   0..73728
  u64*      hs    = (u64*)(smem + 73728);            // [64][17]     ..82432
  unsigned* list  = (unsigned*)(smem + 82432);       // FLAG_CAP u32 ..98816
  unsigned* lcnt  = (unsigned*)(smem + 98816);
  float*    errbL = (float*)(smem + 98832);          // 64 floats
  unsigned* hsw   = (unsigned*)hs;                   // u32 view for atomicXor

  // errb row-sums: hi threads own each row's values once; r12-identical tree
  sAcc += __shfl_xor(sAcc, 16, 64);
  sAcc += __shfl_xor(sAcc, 32, 64);
  if (t == 0) *lcnt = 0;
  if (!isLo && lg == 0)
    errbL[crow] = sAcc * (1.02f / 65536.0f) + 0.125f;
  __syncthreads();

  float eb[4][4];
#pragma unroll
  for (int mf = 0; mf < 4; ++mf)
#pragma unroll
    for (int rg = 0; rg < 4; ++rg) eb[mf][rg] = errbL[mf * 16 + lg * 4 + rg];

#pragma unroll
  for (int mf = 0; mf < 4; ++mf)
#pragma unroll
    for (int nfl = 0; nfl < 9; ++nfl)
#pragma unroll
      for (int rg = 0; rg < 4; ++rg) {
        int bl = mf * 16 + lg * 4 + rg;              // C/D: row = (lane>>4)*4 + reg
        int o  = obase + nfl * 16 + lr;              // C/D: col = lane & 15
        float lin = acc[mf][nfl][rg];
        unsigned abit = (lin >= 0.0f) ? 1u : 0u;
        bits[bl * 1152 + o] = (unsigned char)abit;
        if ((o < O_DIM) && (fabsf(lin) <= eb[mf][rg])) {
          unsigned idx = atomicAdd(lcnt, 1u);
          if (idx < FLAG_CAP)
            list[idx] = ((unsigned)bl << 12) | ((unsigned)o << 1) | abit;
        }
      }
  __syncthreads();

  // pack bits -> h1 words in LDS (pad bits = 1)
  for (int task = t; task < 64 * NWORDS; task += 512) {
    int row = task / NWORDS, w = task % NWORDS;
    u64 word = 0;
#pragma unroll
    for (int q = 0; q < 8; ++q) {
      u64 v = *(const u64*)&bits[row * 1152 + w * 64 + q * 8];
#pragma unroll
      for (int m = 0; m < 8; ++m)
        word |= ((v >> (8 * m)) & 1ull) << (q * 8 + m);
    }
    int rem = O_DIM - w * 64;
    if (rem < 64) word |= (~0ull << rem);
    hs[row * NWORDS + w] = word;
  }
  __syncthreads();

  // in-block exact recompute of flagged elements (bitwise = reference)
  {
    unsigned n = *lcnt; if (n > FLAG_CAP) n = FLAG_CAP;
    for (unsigned i = t; i < n; i += 512) {
      unsigned en = list[i];
      int bl = (int)(en >> 12), o = (int)((en >> 1) & 0x7ffu);
      unsigned abit = en & 1u;
      const float* xr = x + (size_t)(b0 + bl) * K_DIM;
      const u64* wr = w0b + (size_t)o * NWORDS;
      float a = 0.0f;
      for (int j = 0; j < 16; ++j) {    // k strictly ascending, single accumulator
        u64 wd = wr[j];
#pragma unroll
        for (int m = 0; m < 64; ++m) {
          float v = xr[j * 64 + m];
          unsigned neg = ((unsigned)(wd >> m) & 1u) ^ 1u;
          a += __uint_as_float(__float_as_uint(v) ^ (neg << 31));
        }
      }
      {
        u64 wd = wr[16];
        float v = xr[1024];
        unsigned neg = ((unsigned)wd & 1u) ^ 1u;
        a += __uint_as_float(__float_as_uint(v) ^ (neg << 31));
      }
      unsigned nb = (a >= 0.0f) ? 1u : 0u;
      if (nb != abit)
        atomicXor(&hsw[bl * 34 + (o >> 5)], 1u << (o & 31));
    }
  }
  __syncthreads();

  // corrected h1 -> global (coalesced)
  for (int task = t; task < 64 * NWORDS; task += 512)
    h1b[(size_t)b0 * NWORDS + task] = hs[task];
}

// -------- layers 2+3: XOR+popcount (exact); r7-proven lean-VGPR version --------
__global__ __launch_bounds__(256) void l2l3_kernel(const u64* __restrict__ h1b,
                                                   const u64* __restrict__ w1b,
                                                   const u64* __restrict__ w2b,
                                                   float* __restrict__ out) {
  __shared__ u64 hs[L23_ROWS][NWORDS];
  __shared__ u64 h2[L23_ROWS][NWORDS];
  const int bt = blockIdx.x;                 // 1024 blocks x 16 rows
  const int t = threadIdx.x;
  for (int i = t; i < L23_ROWS * NWORDS; i += 256)
    hs[i / NWORDS][i % NWORDS] = h1b[(size_t)(bt * L23_ROWS + i / NWORDS) * NWORDS + i % NWORDS];
  __syncthreads();

  const int w = t >> 6, l = t & 63;
  for (int oc = w; oc < NWORDS; oc += 4) {
    int o = oc * 64 + l;
    bool valid = (o < O_DIM);
    int orow = valid ? o : (O_DIM - 1);
    u64 wb[NWORDS];
#pragma unroll
    for (int j = 0; j < NWORDS; ++j) wb[j] = w1b[(size_t)orow * NWORDS + j];
    for (int b = 0; b < L23_ROWS; b += 2) {   // no unroll: keep regs lean; 2 chains for ILP
      int p0 = 0, p1 = 0;
#pragma unroll
      for (int j = 0; j < NWORDS; ++j) {
        p0 += __popcll(hs[b + 0][j] ^ wb[j]);
        p1 += __popcll(hs[b + 1][j] ^ wb[j]);
      }
      u64 m0 = __ballot(valid ? (K_DIM - 2 * p0 >= 0) : true);   // pad bits = 1
      u64 m1 = __ballot(valid ? (K_DIM - 2 * p1 >= 0) : true);
      if (l == 0) h2[b + 0][oc] = m0;
      if (l == 1) h2[b + 1][oc] = m1;
    }
  }
  __syncthreads();
  if (t < L23_ROWS) {
    int p = 0;
#pragma unroll
    for (int j = 0; j < NWORDS; ++j) p += __popcll(h2[t][j] ^ w2b[j]);
    out[bt * L23_ROWS + t] = ((K_DIM - 2 * p) >= 0) ? 1.0f : 0.0f;
  }
}

extern "C" void kernel_launch(void* const* d_in, const int* in_sizes, int n_in,
                              void* d_out, int out_size, void* d_ws, size_t ws_size,
                              hipStream_t stream) {
  const float* x  = (const float*)d_in[0];
  const float* W0 = (const float*)d_in[1];
  const float* W1 = (const float*)d_in[2];
  const float* W2 = (const float*)d_in[3];
  float* out = (float*)d_out;

  char* ws = (char*)d_ws;
  u64*      w0b  = (u64*)(ws);                   //       0 .. 139776
  u64*      w1b  = (u64*)(ws + 139776);          // .. 279552
  u64*      w2b  = (u64*)(ws + 279552);          // .. 279808
  u64*      h1b  = (u64*)(ws + 280064);          // .. 2508288
  ushort_t* sbf  = (ushort_t*)(ws + 2508288);    // .. 5015040

  static bool attr_set = false;
  if (!attr_set) {
    hipFuncSetAttribute((const void*)l1_fused_kernel,
                        hipFuncAttributeMaxDynamicSharedMemorySize, SMEM_BYTES);
    attr_set = true;
  }

  prep_w_kernel<<<PACK_BLOCKS + SBF_BLOCKS, 256, 0, stream>>>(
      W0, W1, W2, w0b, w1b, w2b, sbf);
  l1_fused_kernel<<<B_TOTAL / 64, 512, SMEM_BYTES, stream>>>(sbf, x, w0b, h1b);
  l2l3_kernel<<<B_TOTAL / L23_ROWS, 256, 0, stream>>>(h1b, w1b, w2b, out);
}